// Round 8
// baseline (383.560 us; speedup 1.0000x reference)
//
#include <hip/hip_runtime.h>
#include <hip/hip_bf16.h>
#include <cstdint>

// ---------------------------------------------------------------------------
// Model: h=relu(x@W1+b1); h=AGNN(h,beta=1); h=AGNN(h,beta2); h=relu(h@W2+b2);
//        out = concat(segmax(h,batch), segmean(h,batch)) @ W3 + b3
// N=30000, E=480000, F_IN=1280, H=512, H2=256, G=64, C=10
// bf16 rows through propagation; 128x256 8-wave MFMA GEMMs, triple-buffered,
// race-free counted-vmcnt pipeline (wait BEFORE barrier, 2-deep A-reg chain);
// XOR-swizzled LDS; DPP wave reduction in AGNN.
// ---------------------------------------------------------------------------

typedef __attribute__((ext_vector_type(8))) short bf16x8;
typedef __attribute__((ext_vector_type(4))) float f32x4;
typedef __attribute__((ext_vector_type(8))) unsigned short ushort8;
typedef __attribute__((ext_vector_type(4))) unsigned short ushort4v;
typedef __attribute__((ext_vector_type(4))) unsigned int uint4v;

#define WAITV(n) asm volatile("s_waitcnt vmcnt(" #n ")" ::: "memory")
#define WAITLGKM asm volatile("s_waitcnt lgkmcnt(0)" ::: "memory")
#define SCHEDB __builtin_amdgcn_sched_barrier(0)

__device__ inline unsigned short f2bf(float f) {
    unsigned int u = __float_as_uint(f);
    u += 0x7FFFu + ((u >> 16) & 1u);   // RNE
    return (unsigned short)(u >> 16);
}

__device__ __forceinline__ float bf2f(unsigned short u) {
    return __uint_as_float(((unsigned int)u) << 16);
}

// packed f32x2 -> bf16x2 (RNE), single HW instruction on gfx950
__device__ __forceinline__ unsigned int cvtpk(float lo, float hi) {
    unsigned int r;
    asm("v_cvt_pk_bf16_f32 %0, %1, %2" : "=v"(r) : "v"(lo), "v"(hi));
    return r;
}

__device__ __forceinline__ void gload_lds16(const void* g, void* l) {
    __builtin_amdgcn_global_load_lds(
        (const __attribute__((address_space(1))) void*)g,
        (__attribute__((address_space(3))) void*)l, 16, 0, 0);
}

// ---- wave64 sum via DPP (VALU pipe, no ds_bpermute). Result uniform. ------
__device__ __forceinline__ float wave_sum_dpp(float p) {
    int t;
    t = __builtin_amdgcn_update_dpp(0, __float_as_int(p), 0xB1, 0xf, 0xf, true);  // quad_perm [1,0,3,2]
    p += __int_as_float(t);
    t = __builtin_amdgcn_update_dpp(0, __float_as_int(p), 0x4E, 0xf, 0xf, true);  // quad_perm [2,3,0,1]
    p += __int_as_float(t);
    t = __builtin_amdgcn_update_dpp(0, __float_as_int(p), 0x141, 0xf, 0xf, true); // row_half_mirror
    p += __int_as_float(t);
    t = __builtin_amdgcn_update_dpp(0, __float_as_int(p), 0x140, 0xf, 0xf, true); // row_mirror
    p += __int_as_float(t);
    t = __builtin_amdgcn_update_dpp(0, __float_as_int(p), 0x142, 0xf, 0xf, true); // row_bcast15
    p += __int_as_float(t);
    t = __builtin_amdgcn_update_dpp(0, __float_as_int(p), 0x143, 0xf, 0xf, true); // row_bcast31
    p += __int_as_float(t);
    return __int_as_float(__builtin_amdgcn_readlane(__float_as_int(p), 63));
}

// ---- tiled transpose: W [K][N] f32 -> Wt [N][K] bf16 (K,N multiples of 32) -
__global__ __launch_bounds__(256) void k_transpose_bf16(
    const float* __restrict__ W, unsigned short* __restrict__ Wt, int K, int N) {
    __shared__ unsigned short t[32][33];
    int k0 = blockIdx.x * 32, n0 = blockIdx.y * 32;
    int tr = threadIdx.x >> 3;          // 0..31
    int tc = (threadIdx.x & 7) * 4;     // 0,4,...,28
    float4 v = *(const float4*)(W + (long)(k0 + tr) * N + n0 + tc);
    t[tr][tc + 0] = f2bf(v.x); t[tr][tc + 1] = f2bf(v.y);
    t[tr][tc + 2] = f2bf(v.z); t[tr][tc + 3] = f2bf(v.w);
    __syncthreads();
    ushort4v o = { t[tc + 0][tr], t[tc + 1][tr], t[tc + 2][tr], t[tc + 3][tr] };
    *(ushort4v*)(Wt + (long)(n0 + tr) * K + k0 + tc) = o;
}

// ---- MFMA GEMM: C[M][N] = relu(A[M][K] @ Bt[N][K]^T + bias) ---------------
// Block tile 128 x BN (BN=256), 512 threads = 8 waves (2m x 4n), wave tile
// 64x64 (acc[4][4]), BK=32. Triple-buffered LDS (72 KB), counted-vmcnt
// pipeline, RACE-FREE form: each step t does
//   issue B(t+2) [+ A(t+3) f32 into regs] ; ds_write A(t+1) (from regs
//   loaded at t-2, already vm-retired -> no stall) ; compute tile t ;
//   s_waitcnt vmcnt(4) (only tile t+2's ops stay in flight) ; lgkmcnt(0) ;
//   s_barrier.
// The pre-barrier waits give every wave's loads/writes a happens-before edge
// to all readers; loads still span 1.5+ K-steps of compute (latency hidden).
// LDS rows 64B; 16B granule g of row r at slot g ^ ((r>>1)&3) (conflict-free,
// both sides: pre-swizzled global source / swizzled ds addrs).
// AF32: A f32 in global, reg-staged 2 tiles deep + packed to bf16.
template <int K, int BN, int NOUT, bool AF32, bool OUTBF16>
__global__ __launch_bounds__(512, 4) void k_gemm_bias_relu(
    const void* __restrict__ Av, const unsigned short* __restrict__ Bt,
    const float* __restrict__ bias, void* __restrict__ Cv, int M) {
    constexpr int NS = K / 32;
    __shared__ unsigned short As[3][128 * 32];
    __shared__ unsigned short Bs[3][BN * 32];
    int tid = threadIdx.x;
    int w = tid >> 6, l = tid & 63;
    int wm = w >> 2, wn = w & 3;
    int mBase = blockIdx.x * 128;
    int nBase = blockIdx.y * BN;

    const float* Af = (const float*)Av;
    const unsigned short* Ab = (const unsigned short*)Av;

    // AF32 reg-staging: thread owns 8 consecutive f32 of one row (4 thr/row)
    int arow = tid >> 2;                          // 0..127
    int aslot = (tid & 3) ^ ((arow >> 1) & 3);    // swizzled 16B slot
    long aRowG = mBase + arow; if (aRowG >= M) aRowG = M - 1;
    const float* aptr = AF32 ? (Af + aRowG * K + (tid & 3) * 8) : nullptr;

    auto stageB = [&](int b, int k0) {
#pragma unroll
        for (int o = 0; o < BN / 128; ++o) {
            int rbase = (w * (BN / 128) + o) * 16;       // wave-uniform
            int row = rbase + (l >> 2);                  // local B row
            int gsrc = (l & 3) ^ ((row >> 1) & 3);       // pre-swizzled src
            gload_lds16(Bt + (long)(nBase + row) * K + k0 + gsrc * 8,
                        &Bs[b][rbase * 32]);
        }
    };
    auto stageAbf = [&](int b, int k0) {
        int rbase = w * 16;
        int row = rbase + (l >> 2);
        int gsrc = (l & 3) ^ ((row >> 1) & 3);
        long gr = mBase + row; if (gr >= M) gr = M - 1;
        gload_lds16(Ab + gr * K + k0 + gsrc * 8, &As[b][rbase * 32]);
    };
    auto loadA = [&](int k0, float4& u0, float4& u1) {
        u0 = *(const float4*)(aptr + k0);
        u1 = *(const float4*)(aptr + k0 + 4);
    };
    auto writeA = [&](int b, float4 u0, float4 u1) {
        uint4v p = { cvtpk(u0.x, u0.y), cvtpk(u0.z, u0.w),
                     cvtpk(u1.x, u1.y), cvtpk(u1.z, u1.w) };
        *(uint4v*)(&As[b][arow * 32 + aslot * 8]) = p;
    };
    auto compute = [&](int cb, f32x4 (&acc)[4][4]) {
        bf16x8 af[4];
#pragma unroll
        for (int m = 0; m < 4; ++m) {
            int ra = wm * 64 + m * 16 + (l & 15);
            int g = (l >> 4) ^ ((ra >> 1) & 3);
            af[m] = *(const bf16x8*)(&As[cb][ra * 32 + g * 8]);
        }
#pragma unroll
        for (int n = 0; n < 4; ++n) {
            int rb = wn * 64 + n * 16 + (l & 15);
            int g = (l >> 4) ^ ((rb >> 1) & 3);
            bf16x8 bfr = *(const bf16x8*)(&Bs[cb][rb * 32 + g * 8]);
#pragma unroll
            for (int m = 0; m < 4; ++m)
                acc[m][n] = __builtin_amdgcn_mfma_f32_16x16x32_bf16(
                    af[m], bfr, acc[m][n], 0, 0, 0);
        }
    };

    f32x4 acc[4][4] = {};
    float4 Ra0 = {}, Ra1 = {}, Rb0 = {}, Rb1 = {};

    // ---- prologue ---------------------------------------------------------
    if constexpr (AF32) {
        loadA(0, Ra0, Ra1);                  // A(0) f32
        stageB(0, 0);
        loadA(32, Rb0, Rb1);                 // A(1) f32
        stageB(1, 32);
        writeA(0, Ra0, Ra1);                 // auto-waits A(0) only
        if (NS > 2) loadA(64, Ra0, Ra1);     // A(2) f32
        WAITV(6);                            // B(0) landed; A(1)/B(1)/A(2) fly
    } else {
        stageAbf(0, 0); stageB(0, 0);
        stageAbf(1, 32); stageB(1, 32);
        WAITV(3);                            // tile0 landed; tile1 in flight
    }
    WAITLGKM;                                // A(0) ds_write committed
    SCHEDB;
    __builtin_amdgcn_s_barrier();            // tile 0 ready for ALL waves

#pragma unroll
    for (int t = 0; t < NS; ++t) {
        const int cb = t % 3, nb = (t + 1) % 3, fb = (t + 2) % 3;
        // ---- issue next work (loads span the barrier) ---------------------
        if constexpr (AF32) {
            if (t + 2 < NS) stageB(fb, (t + 2) * 32);
            if (t + 1 < NS) {                 // regs loaded at t-2: retired
                if ((t & 1) == 0) writeA(nb, Rb0, Rb1);
                else              writeA(nb, Ra0, Ra1);
            }
            if (t + 3 < NS) {
                if ((t & 1) == 0) loadA((t + 3) * 32, Rb0, Rb1);
                else              loadA((t + 3) * 32, Ra0, Ra1);
            }
        } else {
            if (t + 2 < NS) { stageAbf(fb, (t + 2) * 32); stageB(fb, (t + 2) * 32); }
        }
        SCHEDB;
        // ---- compute tile t ----------------------------------------------
        compute(cb, acc);
        // ---- certify tile t+1 landed BEFORE the barrier (race-free) ------
        if (t < NS - 1) {
            if constexpr (AF32) {
                if (t + 3 < NS)      { WAITV(4); }   // B(t+2)+A(t+3) in flight
                else if (t + 2 < NS) { WAITV(2); }   // B(t+2) only
                else                 { WAITV(0); }
            } else {
                if (t + 2 < NS)      { WAITV(3); }   // tile t+2 in flight
                else                 { WAITV(0); }
            }
            WAITLGKM;                  // A(t+1) ds_write committed (in-order DS)
            SCHEDB;
            __builtin_amdgcn_s_barrier();
            SCHEDB;
        }
    }

    // ---- epilogue: row=(l>>4)*4+r, col=l&15 (HW-verified) -----------------
#pragma unroll
    for (int m = 0; m < 4; ++m) {
        int row = mBase + wm * 64 + m * 16 + (l >> 4) * 4;
#pragma unroll
        for (int n = 0; n < 4; ++n) {
            int colg = nBase + wn * 64 + n * 16 + (l & 15);
            float bv = bias[colg];
#pragma unroll
            for (int r = 0; r < 4; ++r) {
                if (row + r < M) {
                    float v = fmaxf(acc[m][n][r] + bv, 0.f);
                    if constexpr (OUTBF16)
                        ((unsigned short*)Cv)[(long)(row + r) * NOUT + colg] = f2bf(v);
                    else
                        ((float*)Cv)[(long)(row + r) * NOUT + colg] = v;
                }
            }
        }
    }
}

// ---- CSR build ------------------------------------------------------------
__global__ void k_csr_init(int* __restrict__ cnt, int* __restrict__ fill, int n) {
    int i = blockIdx.x * blockDim.x + threadIdx.x;
    if (i < n) { cnt[i] = 1; fill[i] = 0; }   // 1 = self loop
}

__global__ void k_csr_count(const int* __restrict__ ei, int* __restrict__ cnt, int E) {
    int e = blockIdx.x * blockDim.x + threadIdx.x;
    if (e < E) atomicAdd(&cnt[ei[E + e]], 1);   // dst row
}

// hierarchical exclusive scan: phase 1 (per-1024-chunk scan + chunk total)
__global__ __launch_bounds__(1024) void k_scan1(const int* __restrict__ cnt,
                                                int* __restrict__ rowp,
                                                int* __restrict__ bsum, int n) {
    __shared__ int wsum[16];
    int b = blockIdx.x, t = threadIdx.x, lane = t & 63, w = t >> 6;
    int i = b * 1024 + t;
    int v = (i < n) ? cnt[i] : 0;
    int x = v;
#pragma unroll
    for (int off = 1; off < 64; off <<= 1) {
        int y = __shfl_up(x, off, 64);
        if (lane >= off) x += y;
    }
    if (lane == 63) wsum[w] = x;
    __syncthreads();
    if (t < 16) {
        int s = wsum[t];
#pragma unroll
        for (int off = 1; off < 16; off <<= 1) {
            int y = __shfl_up(s, off, 64);
            if (t >= off) s += y;
        }
        wsum[t] = s;
    }
    __syncthreads();
    int wo = w ? wsum[w - 1] : 0;
    if (i < n) rowp[i] = wo + x - v;            // chunk-local exclusive
    if (t == 0) bsum[b] = wsum[15];             // chunk total
}

// phase 2: exclusive scan of <=64 chunk totals (single wave)
__global__ __launch_bounds__(64) void k_scan2(int* __restrict__ bsum, int nb) {
    int lane = threadIdx.x;
    int v = (lane < nb) ? bsum[lane] : 0;
    int x = v;
#pragma unroll
    for (int off = 1; off < 64; off <<= 1) {
        int y = __shfl_up(x, off, 64);
        if (lane >= off) x += y;
    }
    int total = __shfl(x, nb - 1, 64);
    if (lane < nb) bsum[lane] = x - v;          // exclusive
    if (lane == 0) bsum[nb] = total;
}

// phase 3: add chunk offsets; write rowp[n] = total
__global__ __launch_bounds__(1024) void k_scan3(const int* __restrict__ bsum,
                                                int* __restrict__ rowp, int n, int nb) {
    int i = blockIdx.x * 1024 + threadIdx.x;
    if (i < n) rowp[i] += bsum[i >> 10];
    else if (i == n) rowp[n] = bsum[nb];
}

__global__ void k_csr_fill(const int* __restrict__ ei, const int* __restrict__ rowp,
                           int* __restrict__ fill, int* __restrict__ col, int E, int n) {
    int idx = blockIdx.x * blockDim.x + threadIdx.x;
    if (idx < E) {
        int d = ei[E + idx];
        int s = ei[idx];
        int pos = atomicAdd(&fill[d], 1);
        col[rowp[d] + pos] = s;
    } else if (idx < E + n) {
        int nd = idx - E;
        int pos = atomicAdd(&fill[nd], 1);
        col[rowp[nd] + pos] = nd;   // self loop
    }
}

// ---- row inverse L2 norm, bf16 rows (H=512) --------------------------------
__global__ __launch_bounds__(256) void k_norm_bf16(const unsigned short* __restrict__ h,
                                                   float* __restrict__ invn, int n) {
    int row = blockIdx.x * 4 + (threadIdx.x >> 6);
    int lane = threadIdx.x & 63;
    if (row >= n) return;
    ushort8 v = *(const ushort8*)(h + (long)row * 512 + lane * 8);
    float s = 0.f;
#pragma unroll
    for (int e = 0; e < 8; ++e) { float f = bf2f(v[e]); s += f * f; }
    s = wave_sum_dpp(s);
    if (lane == 0) invn[row] = 1.f / fmaxf(sqrtf(s), 1e-12f);
}

// ---- AGNN propagation: bf16 rows, one wave per dst, single-pass -----------
// DPP wave reduce (no ds_bpermute in the per-edge chain); readlane broadcasts.
// Optionally fuses the inv-L2-norm of the OUTPUT row (for the next prop).
__global__ __launch_bounds__(256) void k_agnn(
    const unsigned short* __restrict__ h, const float* __restrict__ invn,
    const int* __restrict__ rowp, const int* __restrict__ col,
    const float* __restrict__ beta_ptr, unsigned short* __restrict__ out,
    float* __restrict__ invn_out, int nNodes) {
    int dst = blockIdx.x * 4 + (threadIdx.x >> 6);
    int lane = threadIdx.x & 63;
    if (dst >= nNodes) return;
    float beta = beta_ptr ? beta_ptr[0] : 1.0f;
    ushort8 hdv = *(const ushort8*)(h + (long)dst * 512 + lane * 8);
    float hd[8];
#pragma unroll
    for (int e = 0; e < 8; ++e) hd[e] = bf2f(hdv[e]);
    float coef = beta * invn[dst];
    int s0 = rowp[dst], s1 = rowp[dst + 1];

    float m = -1e30f, ssum = 0.f;
    float acc[8] = {0.f, 0.f, 0.f, 0.f, 0.f, 0.f, 0.f, 0.f};

    for (int base = s0; base < s1; base += 64) {
        int cnt = min(s1 - base, 64);
        int gi = base + lane; if (gi >= s1) gi = s1 - 1;
        int idxl = col[gi];              // batch of up to 64 edge indices
        float vinl = invn[idxl];         // batch of src inv-norms
        int src0 = __builtin_amdgcn_readlane(idxl, 0);
        ushort8 nxt = *(const ushort8*)(h + (long)src0 * 512 + lane * 8);
        for (int j = 0; j < cnt; ++j) {
            ushort8 cur = nxt;
            if (j + 1 < cnt) {
                int sn = __builtin_amdgcn_readlane(idxl, j + 1);
                nxt = *(const ushort8*)(h + (long)sn * 512 + lane * 8);  // prefetch
            }
            float a[8];
#pragma unroll
            for (int e = 0; e < 8; ++e) a[e] = bf2f(cur[e]);
            float p = a[0] * hd[0] + a[1] * hd[1] + a[2] * hd[2] + a[3] * hd[3] +
                      a[4] * hd[4] + a[5] * hd[5] + a[6] * hd[6] + a[7] * hd[7];
            p = wave_sum_dpp(p);         // uniform across wave
            float vin_j = __int_as_float(
                __builtin_amdgcn_readlane(__float_as_int(vinl), j));
            float alpha = coef * vin_j * p;
            if (alpha > m) {             // wave-uniform
                float sc = __expf(m - alpha);
                ssum *= sc;
#pragma unroll
                for (int e = 0; e < 8; ++e) acc[e] *= sc;
                m = alpha;
            }
            float wgt = __expf(alpha - m);
            ssum += wgt;
#pragma unroll
            for (int e = 0; e < 8; ++e) acc[e] += wgt * a[e];
        }
    }
    float inv_s = 1.f / ssum;
#pragma unroll
    for (int e = 0; e < 8; ++e) acc[e] *= inv_s;

    uint4v o = { cvtpk(acc[0], acc[1]), cvtpk(acc[2], acc[3]),
                 cvtpk(acc[4], acc[5]), cvtpk(acc[6], acc[7]) };
    *(uint4v*)(out + (long)dst * 512 + lane * 8) = o;

    if (invn_out) {                      // fused output norm (feeds next prop)
        float s = 0.f;
#pragma unroll
        for (int e = 0; e < 8; ++e) s += acc[e] * acc[e];
        s = wave_sum_dpp(s);
        if (lane == 0) invn_out[dst] = 1.f / fmaxf(sqrtf(s), 1e-12f);
    }
}

// ---- graph boundaries in sorted batch -------------------------------------
__global__ void k_bounds(const int* __restrict__ batch, int* __restrict__ starts,
                         int n, int G) {
    int g = blockIdx.x * blockDim.x + threadIdx.x;
    if (g > G) return;
    int lo = 0, hi = n;
    while (lo < hi) {
        int mid = (lo + hi) >> 1;
        if (batch[mid] < g) lo = mid + 1; else hi = mid;
    }
    starts[g] = lo;
}

// ---- per-graph max/mean pool (H2=256) -------------------------------------
__global__ __launch_bounds__(256) void k_pool(const float* __restrict__ h3,
                                              const int* __restrict__ starts,
                                              float* __restrict__ pooled) {
    int g = blockIdx.x;
    int t = threadIdx.x;
    int s = starts[g], e = starts[g + 1];
    float mx = -3.402823466e38f, sm = 0.f;
    int r = s;
    for (; r + 4 <= e; r += 4) {          // ILP unroll
        float v0 = h3[(long)(r + 0) * 256 + t];
        float v1 = h3[(long)(r + 1) * 256 + t];
        float v2 = h3[(long)(r + 2) * 256 + t];
        float v3 = h3[(long)(r + 3) * 256 + t];
        mx = fmaxf(mx, fmaxf(fmaxf(v0, v1), fmaxf(v2, v3)));
        sm += (v0 + v1) + (v2 + v3);
    }
    for (; r < e; ++r) {
        float v = h3[(long)r * 256 + t];
        mx = fmaxf(mx, v); sm += v;
    }
    float cnt = fmaxf((float)(e - s), 1.f);
    pooled[g * 512 + t] = mx;
    pooled[g * 512 + 256 + t] = sm / cnt;
}

// ---- final tiny GEMM: out[G][C] = pooled[G][512] @ W3[512][C] + b3 --------
__global__ __launch_bounds__(64) void k_final(const float* __restrict__ pooled,
                                              const float* __restrict__ W3,
                                              const float* __restrict__ b3,
                                              float* __restrict__ out, int C) {
    int g = blockIdx.x;
    int lane = threadIdx.x;
    for (int c = 0; c < C; c++) {
        float p = 0.f;
        for (int k = lane; k < 512; k += 64) p += pooled[g * 512 + k] * W3[k * C + c];
#pragma unroll
        for (int off = 32; off; off >>= 1) p += __shfl_xor(p, off, 64);
        if (lane == 0) out[g * C + c] = p + b3[c];
    }
}

// ---------------------------------------------------------------------------
extern "C" void kernel_launch(void* const* d_in, const int* in_sizes, int n_in,
                              void* d_out, int out_size, void* d_ws, size_t ws_size,
                              hipStream_t stream) {
    const float* x     = (const float*)d_in[0];
    const int*   ei    = (const int*)d_in[1];
    const int*   batch = (const int*)d_in[2];
    const float* W1    = (const float*)d_in[3];
    const float* b1    = (const float*)d_in[4];
    const float* beta2 = (const float*)d_in[5];
    const float* W2    = (const float*)d_in[6];
    const float* b2    = (const float*)d_in[7];
    const float* W3    = (const float*)d_in[8];
    const float* b3    = (const float*)d_in[9];
    float* out = (float*)d_out;

    const int N = in_sizes[2];          // 30000
    const int E = in_sizes[1] / 2;      // 480000
    const int F_IN = in_sizes[0] / N;   // 1280
    const int H = in_sizes[4];          // 512
    const int H2 = in_sizes[7];         // 256
    const int C = in_sizes[9];          // 10
    const int G = out_size / C;         // 64

    char* ws = (char*)d_ws;
    unsigned short* H1B = (unsigned short*)(ws + 0);            // 30.72 MB bf16
    unsigned short* HPB = (unsigned short*)(ws + 31000000L);    // 30.72 MB bf16
    unsigned short* H2B = (unsigned short*)(ws + 62000000L);    // 30.72 MB bf16
    float*          H3  = (float*)(ws + 0);                     // 61.44 MB f32 (over H1B/HPB, both dead)
    unsigned short* W1T = (unsigned short*)(ws + 93000000L);    // 1.31 MB
    unsigned short* W2T = (unsigned short*)(ws + 94500000L);    // 0.26 MB
    float* INVN_A = (float*)(ws + 95000000L);                   // 120 KB
    float* INVN_B = (float*)(ws + 95200000L);                   // 120 KB
    int*   CNT    = (int*)(ws + 95400000L);
    int*   FILL   = (int*)(ws + 95600000L);
    int*   ROWP   = (int*)(ws + 95800000L);
    int*   COL    = (int*)(ws + 96000000L);                     // 2.04 MB
    int*   BSUM   = (int*)(ws + 98100000L);
    int*   START  = (int*)(ws + 98110000L);
    float* POOLED = (float*)(ws + 98120000L);                   // 131 KB

    // 1. weight transposes (f32 -> bf16 [N][K])
    { dim3 g1(F_IN / 32, H / 32); k_transpose_bf16<<<g1, 256, 0, stream>>>(W1, W1T, F_IN, H); }
    { dim3 g2(H / 32, H2 / 32);   k_transpose_bf16<<<g2, 256, 0, stream>>>(W2, W2T, H, H2); }

    // 2. CSR (incoming edges + self loops)
    int nb = (N + 1023) / 1024;   // 30
    k_csr_init<<<(N + 255) / 256, 256, 0, stream>>>(CNT, FILL, N);
    k_csr_count<<<(E + 255) / 256, 256, 0, stream>>>(ei, CNT, E);
    k_scan1<<<nb, 1024, 0, stream>>>(CNT, ROWP, BSUM, N);
    k_scan2<<<1, 64, 0, stream>>>(BSUM, nb);
    k_scan3<<<(N + 1 + 1023) / 1024, 1024, 0, stream>>>(BSUM, ROWP, N, nb);
    k_csr_fill<<<(E + N + 255) / 256, 256, 0, stream>>>(ei, ROWP, FILL, COL, E, N);

    // 3. GEMM1: H1B = bf16(relu(x @ W1 + b1))  [N,512]; 128x256 tiles
    {
        dim3 grid((N + 127) / 128, H / 256);
        k_gemm_bias_relu<1280, 256, 512, true, true>
            <<<grid, 512, 0, stream>>>(x, W1T, b1, H1B, N);
    }

    // 4. prop1 (beta=1): HPB = AGNN(H1B), fused invn of HPB -> INVN_B
    k_norm_bf16<<<(N + 3) / 4, 256, 0, stream>>>(H1B, INVN_A, N);
    k_agnn<<<(N + 3) / 4, 256, 0, stream>>>(H1B, INVN_A, ROWP, COL, nullptr, HPB, INVN_B, N);

    // 5. prop2 (beta=beta2): H2B = AGNN(HPB)
    k_agnn<<<(N + 3) / 4, 256, 0, stream>>>(HPB, INVN_B, ROWP, COL, beta2, H2B, nullptr, N);

    // 6. GEMM2: H3 = relu(H2B @ W2 + b2)  [N,256] f32; BN=256 read-once A
    {
        dim3 grid((N + 127) / 128, 1);
        k_gemm_bias_relu<512, 256, 256, false, false>
            <<<grid, 512, 0, stream>>>(H2B, W2T, b2, H3, N);
    }

    // 7. pool + final linear
    k_bounds<<<1, 128, 0, stream>>>(batch, START, N, G);
    k_pool<<<G, 256, 0, stream>>>(H3, START, POOLED);
    k_final<<<G, 64, 0, stream>>>(POOLED, W3, b3, out, C);
}